// Round 7
// baseline (1317.371 us; speedup 1.0000x reference)
//
#include <hip/hip_runtime.h>
#include <cstdint>
#include <cstddef>

#define BATCH 128
#define TLEN 4096
#define KS 64
#define NCHUNK 64  // chunk c covers t in [64c+1, min(64c+64, 4095)]

typedef __attribute__((ext_vector_type(4))) float f4;

__device__ __forceinline__ float f3(float a, float b, float c) {
  return fmaxf(fmaxf(a, b), c);  // folds to v_max3_f32
}

// max over m[64] without clobbering m. fp32 max returns an input bitwise,
// so any tree shape gives states bit-identical to the reference.
__device__ __forceinline__ float tree64(const float* m) {
  float t[22];
#pragma unroll
  for (int i = 0; i < 21; ++i) t[i] = f3(m[3 * i], m[3 * i + 1], m[3 * i + 2]);
  t[21] = m[63];
#pragma unroll
  for (int i = 0; i < 7; ++i) t[i] = f3(t[3 * i], t[3 * i + 1], t[3 * i + 2]);
  t[7] = t[21];
  t[0] = f3(t[0], t[1], t[2]);
  t[1] = f3(t[3], t[4], t[5]);
  t[2] = t[6];
  t[3] = t[7];
  t[0] = f3(t[0], t[1], t[2]);
  return fmaxf(t[0], t[3]);
}

// ===========================================================================
// R7: 4-wave hand-asm forward chain.
// R6 hit the single-wave ISSUE floor (479 cyc/step: 192 cyc of ds_read
// issue + 148 VALU + waits). R7 splits the i-reduction across 4 waves
// (wave w owns i in [16w,16w+16)):
//   - per-wave VALU: 16 v_add + 8-op max3 reduce (vs 74 ops)
//   - state broadcast REPLACED by v_readlane: after the combine every wave
//     holds full s[j] in lane j, so the 16 uniform s[i] come from the
//     register file (no LDS, no lgkm) — kills the 192-cyc read stream
//   - cross-wave exchange: 1 ds_write_b32 + ONE s_barrier + 2 ds_read2_b32,
//     parity double-buffered (write(P), bar, read(P); reuse of P is 2
//     barriers later -> race-free with a single barrier per step)
//   - counted vmcnt(3) emission ring survives the barrier (the exact thing
//     the compiler refused in R2 — it drained vmcnt(0) at every barrier)
// Register map: v32-47 T, v160-175 adds, v176 s, v177-180 e-ring,
// v181-187 temps/partials, v183 pbuf waddr, v188/189 pbuf rbase P1/P0,
// v190/191 temps, v192:193 em addr, v194:195 cp addr, v196:197 fin addr.
// SGPRs: s20 ctr, s21 tmp, s23 wave-id, s24-39 lane idx, s40-55 uniforms.
// 4095 steps = 3 HIP pre-steps + 1023 asm groups of 4.
// ===========================================================================

#define RL16 \
  "v_readlane_b32 s40, v176, s24\n" \
  "v_readlane_b32 s41, v176, s25\n" \
  "v_readlane_b32 s42, v176, s26\n" \
  "v_readlane_b32 s43, v176, s27\n" \
  "v_readlane_b32 s44, v176, s28\n" \
  "v_readlane_b32 s45, v176, s29\n" \
  "v_readlane_b32 s46, v176, s30\n" \
  "v_readlane_b32 s47, v176, s31\n" \
  "v_readlane_b32 s48, v176, s32\n" \
  "v_readlane_b32 s49, v176, s33\n" \
  "v_readlane_b32 s50, v176, s34\n" \
  "v_readlane_b32 s51, v176, s35\n" \
  "v_readlane_b32 s52, v176, s36\n" \
  "v_readlane_b32 s53, v176, s37\n" \
  "v_readlane_b32 s54, v176, s38\n" \
  "v_readlane_b32 s55, v176, s39\n"

#define ADD16 \
  "v_add_f32 v160, s40, v32\n" \
  "v_add_f32 v161, s41, v33\n" \
  "v_add_f32 v162, s42, v34\n" \
  "v_add_f32 v163, s43, v35\n" \
  "v_add_f32 v164, s44, v36\n" \
  "v_add_f32 v165, s45, v37\n" \
  "v_add_f32 v166, s46, v38\n" \
  "v_add_f32 v167, s47, v39\n" \
  "v_add_f32 v168, s48, v40\n" \
  "v_add_f32 v169, s49, v41\n" \
  "v_add_f32 v170, s50, v42\n" \
  "v_add_f32 v171, s51, v43\n" \
  "v_add_f32 v172, s52, v44\n" \
  "v_add_f32 v173, s53, v45\n" \
  "v_add_f32 v174, s54, v46\n" \
  "v_add_f32 v175, s55, v47\n"

#define RED16 \
  "v_max3_f32 v181, v160, v161, v162\n" \
  "v_max3_f32 v182, v163, v164, v165\n" \
  "v_max3_f32 v184, v166, v167, v168\n" \
  "v_max3_f32 v185, v169, v170, v171\n" \
  "v_max3_f32 v186, v172, v173, v174\n" \
  "v_max3_f32 v187, v181, v182, v184\n" \
  "v_max3_f32 v190, v185, v186, v175\n" \
  "v_max_f32 v190, v187, v190\n"

// one time-step. EK = ring reg, LDOFF = next-emission offset,
// WOFF = pbuf write parity offset (0/1024), RBASE = pbuf read base
// (v189 parity0 / v188 parity1), EXTRA = checkpoint block or empty.
#define POS(EK, LDOFF, WOFF, RBASE, EXTRA) \
  RL16 \
  ADD16 \
  RED16 \
  "ds_write_b32 v183, v190 offset:" WOFF "\n" \
  "s_waitcnt lgkmcnt(0)\n" \
  "s_barrier\n" \
  "ds_read2_b32 v[184:185], " RBASE " offset0:0 offset1:64\n" \
  "ds_read2_b32 v[186:187], " RBASE " offset0:128 offset1:192\n" \
  "s_waitcnt lgkmcnt(0)\n" \
  "v_max3_f32 v191, v184, v185, v186\n" \
  "v_max_f32 v191, v191, v187\n" \
  "s_waitcnt vmcnt(3)\n" \
  "v_add_f32 v176, v191, " EK "\n" \
  EXTRA \
  "global_load_dword " EK ", v[192:193], off offset:" LDOFF "\n"

// checkpoint: wave 0 only, every 16th group (s20&15==0). Stores the freshly
// combined v176 = s_t (t = 4*(1023-s20)+4 = 64,128,...,4032 -> cp rows 1..63)
#define CPBLK \
  "s_and_b32 s21, s20, 15\n" \
  "s_or_b32 s21, s21, s23\n" \
  "s_cmp_eq_u32 s21, 0\n" \
  "s_cbranch_scc0 NOCP%=\n" \
  "global_store_dword v[194:195], v176, off\n" \
  "v_add_co_u32 v194, vcc, 0x100, v194\n" \
  "v_addc_co_u32 v195, vcc, 0, v195, vcc\n" \
  "s_waitcnt vmcnt(0)\n" \
  "NOCP%=:\n"

__global__ __launch_bounds__(256, 1) void crf_fwd(
    const float* __restrict__ pot, const float* __restrict__ trans,
    float* __restrict__ cp, float* __restrict__ fin) {
  const int b = blockIdx.x;
  const int tid = threadIdx.x;
  const int w = tid >> 6;  // wave id 0..3, owns i in [16w,16w+16)
  const int j = tid & 63;  // column
  __shared__ float smf[KS];           // pre-step state broadcast (256 B)
  __shared__ float pbuf[2 * 4 * KS];  // asm partial buffers (2 KB)

  const float* pb = pot + (size_t)b * TLEN * KS + j;
  float* cpb = cp + (size_t)b * NCHUNK * KS + j;

  float s = pb[0];
  if (w == 0) {
    cpb[0] = s;
    smf[j] = s;
  }
  __syncthreads();

  // 3 HIP pre-steps (t=1..3), computed redundantly by all 4 waves
  // (identical inputs -> identical s). 4095 = 3 + 4*1023.
  for (int t = 1; t <= 3; ++t) {
    float p[16];
#pragma unroll
    for (int q = 0; q < 16; ++q) {
      float a0 = smf[4 * q + 0] + trans[(4 * q + 0) * KS + j];
      float a1 = smf[4 * q + 1] + trans[(4 * q + 1) * KS + j];
      float a2 = smf[4 * q + 2] + trans[(4 * q + 2) * KS + j];
      float a3 = smf[4 * q + 3] + trans[(4 * q + 3) * KS + j];
      p[q] = fmaxf(f3(a0, a1, a2), a3);
    }
    float u0 = f3(p[0], p[1], p[2]);
    float u1 = f3(p[3], p[4], p[5]);
    float u2 = f3(p[6], p[7], p[8]);
    float u3 = f3(p[9], p[10], p[11]);
    float u4 = f3(p[12], p[13], p[14]);
    float sn = fmaxf(f3(u0, u1, u2), f3(u3, u4, p[15])) + pb[(size_t)t * KS];
    __syncthreads();
    if (w == 0) smf[j] = sn;
    __syncthreads();
    s = sn;
  }

  // asm operand setup (low-32 of a flat LDS pointer == LDS byte offset —
  // validated by R6 on this hardware)
  uint32_t pba = (uint32_t)(uintptr_t)pbuf;
  uint32_t wa = pba + 256u * (uint32_t)w + 4u * (uint32_t)j;  // write slot
  uint32_t ra = pba + 4u * (uint32_t)j;                       // read base P0
  uint64_t tca = (uint64_t)(uintptr_t)(trans + (size_t)(16 * w) * KS + j);
  uint64_t em = (uint64_t)(uintptr_t)(pb + (size_t)4 * KS);  // row t=4
  uint64_t cpa = (uint64_t)(uintptr_t)(cpb + KS);            // cp row 1
  uint64_t fa = (uint64_t)(uintptr_t)(fin + (size_t)b * KS + j);
  int w16 = __builtin_amdgcn_readfirstlane(16 * w);

  asm volatile(
      // ---- prologue ----
      "s_waitcnt vmcnt(0) lgkmcnt(0)\n"
      "v_mov_b32 v176, %[sinit]\n"
      "v_mov_b32 v183, %[wa]\n"
      "v_mov_b32 v189, %[ra]\n"
      "v_add_u32 v188, 0x400, v189\n"
      // T rows 16w..16w+15, column j -> v32..v47 (coalesced, stride 256 B)
      "v_mov_b32 v192, %[tclo]\n"
      "v_mov_b32 v193, %[tchi]\n"
      "global_load_dword v32, v[192:193], off offset:0\n"
      "global_load_dword v33, v[192:193], off offset:256\n"
      "global_load_dword v34, v[192:193], off offset:512\n"
      "global_load_dword v35, v[192:193], off offset:768\n"
      "global_load_dword v36, v[192:193], off offset:1024\n"
      "global_load_dword v37, v[192:193], off offset:1280\n"
      "global_load_dword v38, v[192:193], off offset:1536\n"
      "global_load_dword v39, v[192:193], off offset:1792\n"
      "global_load_dword v40, v[192:193], off offset:2048\n"
      "global_load_dword v41, v[192:193], off offset:2304\n"
      "global_load_dword v42, v[192:193], off offset:2560\n"
      "global_load_dword v43, v[192:193], off offset:2816\n"
      "global_load_dword v44, v[192:193], off offset:3072\n"
      "global_load_dword v45, v[192:193], off offset:3328\n"
      "global_load_dword v46, v[192:193], off offset:3584\n"
      "global_load_dword v47, v[192:193], off offset:3840\n"
      // emission ring: rows t=4..7
      "v_mov_b32 v192, %[emlo]\n"
      "v_mov_b32 v193, %[emhi]\n"
      "global_load_dword v177, v[192:193], off offset:0\n"
      "global_load_dword v178, v[192:193], off offset:256\n"
      "global_load_dword v179, v[192:193], off offset:512\n"
      "global_load_dword v180, v[192:193], off offset:768\n"
      "v_mov_b32 v194, %[cplo]\n"
      "v_mov_b32 v195, %[cphi]\n"
      "v_mov_b32 v196, %[fnlo]\n"
      "v_mov_b32 v197, %[fnhi]\n"
      // lane-index SGPRs s24..s39 = 16w..16w+15; s23 = wave id
      "s_mov_b32 s24, %[w16]\n"
      "s_lshr_b32 s23, s24, 4\n"
      "s_add_u32 s25, s24, 1\n"
      "s_add_u32 s26, s24, 2\n"
      "s_add_u32 s27, s24, 3\n"
      "s_add_u32 s28, s24, 4\n"
      "s_add_u32 s29, s24, 5\n"
      "s_add_u32 s30, s24, 6\n"
      "s_add_u32 s31, s24, 7\n"
      "s_add_u32 s32, s24, 8\n"
      "s_add_u32 s33, s24, 9\n"
      "s_add_u32 s34, s24, 10\n"
      "s_add_u32 s35, s24, 11\n"
      "s_add_u32 s36, s24, 12\n"
      "s_add_u32 s37, s24, 13\n"
      "s_add_u32 s38, s24, 14\n"
      "s_add_u32 s39, s24, 15\n"
      // wait T loads done (4 ring loads may stay outstanding)
      "s_waitcnt vmcnt(4)\n"
      "s_mov_b32 s20, 1023\n"
      // ---- main loop: 1023 groups x 4 steps ----
      "CRFLOOP%=:\n"
      // last group: rewind emis base 4096 B so prefetches stay in-bounds
      "s_cmp_eq_u32 s20, 1\n"
      "s_cbranch_scc0 NOADJ%=\n"
      "v_add_co_u32 v192, vcc, 0xfffff000, v192\n"
      "v_addc_co_u32 v193, vcc, -1, v193, vcc\n"
      "NOADJ%=:\n"
      POS("v177", "1024", "0", "v189", CPBLK)
      POS("v178", "1280", "1024", "v188", "")
      POS("v179", "1536", "0", "v189", "")
      POS("v180", "1792", "1024", "v188", "")
      // advance emission base one group (4 rows = 1024 B)
      "v_add_co_u32 v192, vcc, 0x400, v192\n"
      "v_addc_co_u32 v193, vcc, 0, v193, vcc\n"
      "s_sub_u32 s20, s20, 1\n"
      "s_cmp_lg_u32 s20, 0\n"
      "s_cbranch_scc1 CRFLOOP%=\n"
      // ---- epilogue: final state (wave 0 stores) ----
      "s_cmp_lg_u32 s23, 0\n"
      "s_cbranch_scc1 SKIPFIN%=\n"
      "global_store_dword v[196:197], v176, off\n"
      "SKIPFIN%=:\n"
      "s_waitcnt vmcnt(0)\n"
      :
      : [sinit] "v"(s), [wa] "v"(wa), [ra] "v"(ra),
        [tclo] "v"((uint32_t)tca), [tchi] "v"((uint32_t)(tca >> 32)),
        [emlo] "v"((uint32_t)em), [emhi] "v"((uint32_t)(em >> 32)),
        [cplo] "v"((uint32_t)cpa), [cphi] "v"((uint32_t)(cpa >> 32)),
        [fnlo] "v"((uint32_t)fa), [fnhi] "v"((uint32_t)(fa >> 32)),
        [w16] "s"(w16)
      : "memory", "vcc", "scc",
        "s20", "s21", "s23", "s24", "s25", "s26", "s27", "s28", "s29", "s30",
        "s31", "s32", "s33", "s34", "s35", "s36", "s37", "s38", "s39", "s40",
        "s41", "s42", "s43", "s44", "s45", "s46", "s47", "s48", "s49", "s50",
        "s51", "s52", "s53", "s54", "s55",
        "v32", "v33", "v34", "v35", "v36", "v37", "v38", "v39", "v40", "v41",
        "v42", "v43", "v44", "v45", "v46", "v47",
        "v160", "v161", "v162", "v163", "v164", "v165", "v166", "v167",
        "v168", "v169", "v170", "v171", "v172", "v173", "v174", "v175",
        "v176", "v177", "v178", "v179", "v180", "v181", "v182", "v183",
        "v184", "v185", "v186", "v187", "v188", "v189", "v190", "v191",
        "v192", "v193", "v194", "v195", "v196", "v197");
}

// ---------------------------------------------------------------------------
// Backpointer reconstruction (unchanged, best-measured rest-of-pipeline):
// per (batch, chunk) wave recomputes states from the checkpoint
// (bit-identical: fp32 max is exact, sums identical), derives bp[t][j],
// and fuses the speculative chunk-map chase via ds_bpermute.
// 8192 waves -> latency hidden by TLP.
// ---------------------------------------------------------------------------
__global__ __launch_bounds__(64) void crf_bp(
    const float* __restrict__ pot, const float* __restrict__ trans,
    const float* __restrict__ cp, unsigned char* __restrict__ bp,
    unsigned char* __restrict__ map) {
  const int b = blockIdx.x;
  const int ch = blockIdx.y;
  const int j = threadIdx.x;
  __shared__ float4 sm4[KS / 4];
  float* sm = (float*)sm4;

  float c[KS];
#pragma unroll
  for (int i = 0; i < KS; ++i) c[i] = trans[i * KS + j];

  float s = cp[((size_t)b * NCHUNK + ch) * KS + j];
  const int t0 = ch * 64;
  const int hi = min(t0 + 64, TLEN - 1);
  const float* pb = pot + (size_t)b * TLEN * KS + j;
  unsigned char* bpb = bp + (size_t)b * TLEN * KS + j;

  sm[j] = s;
  int tag = j;  // forward-composed backward map
  float emit = pb[(size_t)(t0 + 1) * KS];
  for (int t = t0 + 1; t <= hi; ++t) {
    float emit_next = pb[(size_t)min(t + 1, TLEN - 1) * KS];

    float m[KS];
#pragma unroll
    for (int q = 0; q < KS / 4; ++q) {
      float4 v = sm4[q];
      m[4 * q + 0] = v.x + c[4 * q + 0];
      m[4 * q + 1] = v.y + c[4 * q + 1];
      m[4 * q + 2] = v.z + c[4 * q + 2];
      m[4 * q + 3] = v.w + c[4 * q + 3];
    }
    float best = tree64(m);

    // first-occurrence argmax: descending exact-equality scan
    int bi = 63;
#pragma unroll
    for (int i = 62; i >= 0; --i) bi = (m[i] == best) ? i : bi;

    bpb[(size_t)t * KS] = (unsigned char)bi;
    s = best + emit;
    sm[j] = s;
    emit = emit_next;

    // g_t[k] = g_{t-1}[bp_t[k]]: lane k pulls lane bi_k's tag
    tag = __builtin_amdgcn_ds_bpermute(bi << 2, tag);
  }
  map[((size_t)b * NCHUNK + ch) * KS + j] = (unsigned char)tag;
}

// ---------------------------------------------------------------------------
// Compose chunk maps per batch (serial over 64 chunks, parallel over batches).
// Also does the final-state argmax (first-occurrence, strict >).
// ---------------------------------------------------------------------------
__global__ void crf_compose(const unsigned char* __restrict__ map,
                            const float* __restrict__ fin,
                            unsigned char* __restrict__ e,
                            int* __restrict__ tags_out) {
  const int b = blockIdx.x * blockDim.x + threadIdx.x;
  if (b >= BATCH) return;
  const float* fb = fin + (size_t)b * KS;
  float best = fb[0];
  int cur = 0;
  for (int i = 1; i < KS; ++i) {
    float v = fb[i];
    if (v > best) { best = v; cur = i; }
  }
  tags_out[(size_t)b * TLEN + (TLEN - 1)] = cur;
  for (int ch = NCHUNK - 1; ch >= 0; --ch) {
    e[(size_t)b * NCHUNK + ch] = (unsigned char)cur;
    cur = map[((size_t)b * NCHUNK + ch) * KS + cur];
  }
}

// ---------------------------------------------------------------------------
// Extract per-chunk paths from known entering tags (parallel over B*NCHUNK).
// ---------------------------------------------------------------------------
__global__ void crf_extract(const unsigned char* __restrict__ bp,
                            const unsigned char* __restrict__ e,
                            int* __restrict__ tags_out) {
  const int idx = blockIdx.x * blockDim.x + threadIdx.x;  // b*NCHUNK + c
  if (idx >= BATCH * NCHUNK) return;
  const int b = idx >> 6;
  const int c = idx & (NCHUNK - 1);
  const int lo = 64 * c + 1;
  const int hi = min(64 * c + 64, TLEN - 1);
  const unsigned char* bpb = bp + (size_t)b * TLEN * KS;
  int* to = tags_out + (size_t)b * TLEN;
  int tag = e[(size_t)b * NCHUNK + c];
  for (int t = hi; t >= lo; --t) {
    tag = bpb[(size_t)t * KS + tag];
    to[t - 1] = tag;
  }
}

// ---------------------------------------------------------------------------
// Sequence lengths = sum(mask) per batch.
// ---------------------------------------------------------------------------
__global__ __launch_bounds__(64) void crf_lens(const int* __restrict__ mask,
                                               int* __restrict__ out) {
  const int b = blockIdx.x;
  const int l = threadIdx.x;
  const int* mb = mask + (size_t)b * TLEN;
  int sum = 0;
  for (int t = l; t < TLEN; t += 64) sum += mb[t];
#pragma unroll
  for (int off = 32; off > 0; off >>= 1) sum += __shfl_down(sum, off, 64);
  if (l == 0) out[b] = sum;
}

extern "C" void kernel_launch(void* const* d_in, const int* in_sizes, int n_in,
                              void* d_out, int out_size, void* d_ws,
                              size_t ws_size, hipStream_t stream) {
  const float* pot = (const float*)d_in[0];    // (128, 4096, 64) fp32
  const float* trans = (const float*)d_in[1];  // (64, 64) fp32
  const int* mask = (const int*)d_in[2];       // (128, 4096) int32

  int* out = (int*)d_out;  // [tags: 128*4096][lens: 128]
  int* tags_out = out;
  int* lens_out = out + (size_t)BATCH * TLEN;

  // workspace layout
  char* w = (char*)d_ws;
  unsigned char* bp = (unsigned char*)w;                     // 33,554,432 B
  float* cp = (float*)(bp + (size_t)BATCH * TLEN * KS);      //  2,097,152 B
  float* fin = cp + (size_t)BATCH * NCHUNK * KS;             //     32,768 B
  unsigned char* map = (unsigned char*)(fin + (size_t)BATCH * KS);  // 524,288 B
  unsigned char* e = map + (size_t)BATCH * NCHUNK * KS;      //      8,192 B

  crf_fwd<<<BATCH, 256, 0, stream>>>(pot, trans, cp, fin);
  crf_lens<<<BATCH, 64, 0, stream>>>(mask, lens_out);
  crf_bp<<<dim3(BATCH, NCHUNK), 64, 0, stream>>>(pot, trans, cp, bp, map);
  crf_compose<<<1, BATCH, 0, stream>>>(map, fin, e, tags_out);
  crf_extract<<<(BATCH * NCHUNK + 255) / 256, 256, 0, stream>>>(bp, e, tags_out);
}